// Round 1
// baseline (306.256 us; speedup 1.0000x reference)
//
#include <hip/hip_runtime.h>
#include <hip/hip_bf16.h>

// ---------------------------------------------------------------------------
// BehaviorSpecificPFF: token-routed 4-expert FFN.
//   y[tok] = relu(x[tok] @ W1[g] + B1[g]) @ W2[g] + B2[g],  g = b_seq[tok]-1
//   b_seq==0 -> zeros.
// Strategy: gather tokens per expert -> grouped bf16 MFMA GEMM x2 via packed
// intermediate H in workspace. Weights pre-transposed+converted to bf16 so
// B-fragments are contiguous-k ds_read_b128.
// ---------------------------------------------------------------------------

typedef short s16x8 __attribute__((ext_vector_type(8)));
typedef float f32x4 __attribute__((ext_vector_type(4)));

#define NTOK   16384
#define HDIM   512
#define FDIM   2048
#define NEXP   4

// ---- header layout (ints) in ws ----
// [0..3]  counts per expert
// [4..7]  cursors (fill)
// [8..12] token offsets (exclusive prefix, [12]=total)
// [13..17] gemm1 tile bases ([17]=total tiles)
// [18..22] gemm2 tile bases ([22]=total tiles)

__global__ void k_init(float4* __restrict__ out, int n4, int* __restrict__ hdr) {
  if (blockIdx.x == 0 && threadIdx.x < 32) hdr[threadIdx.x] = 0;
  float4 z; z.x = z.y = z.z = z.w = 0.f;
  for (int i = blockIdx.x * blockDim.x + threadIdx.x; i < n4;
       i += gridDim.x * blockDim.x)
    out[i] = z;
}

__global__ void k_count(const int* __restrict__ b_seq, int* __restrict__ hdr) {
  int i = blockIdx.x * blockDim.x + threadIdx.x;  // exactly NTOK threads
  int g = b_seq[i];
  if (g > 0) atomicAdd(&hdr[g - 1], 1);
}

__global__ void k_scan(int* __restrict__ hdr) {
  if (threadIdx.x != 0 || blockIdx.x != 0) return;
  int off = 0, b1 = 0, b2 = 0;
  for (int g = 0; g < 4; ++g) {
    int c = hdr[g];
    hdr[8 + g] = off;
    hdr[4 + g] = off;   // cursor starts at offset
    hdr[13 + g] = b1;
    hdr[18 + g] = b2;
    int mt = (c + 127) >> 7;
    off += c;
    b1 += mt * (FDIM / 128);  // 16 n-tiles
    b2 += mt * (HDIM / 128);  // 4 n-tiles
  }
  hdr[12] = off; hdr[17] = b1; hdr[22] = b2;
}

__global__ void k_fill(const int* __restrict__ b_seq, int* __restrict__ hdr,
                       int* __restrict__ perm) {
  int i = blockIdx.x * blockDim.x + threadIdx.x;
  int g = b_seq[i];
  if (g > 0) {
    int p = atomicAdd(&hdr[4 + g - 1], 1);
    perm[p] = i;
  }
}

__global__ void k_cvt_x(const float* __restrict__ x,
                        __hip_bfloat16* __restrict__ xb, int n4) {
  union { __hip_bfloat16 b[4]; uint2 u; } t;
  for (int i = blockIdx.x * blockDim.x + threadIdx.x; i < n4;
       i += gridDim.x * blockDim.x) {
    float4 v = ((const float4*)x)[i];
    t.b[0] = __float2bfloat16(v.x);
    t.b[1] = __float2bfloat16(v.y);
    t.b[2] = __float2bfloat16(v.z);
    t.b[3] = __float2bfloat16(v.w);
    ((uint2*)xb)[i] = t.u;
  }
}

// dst[g][c][r] = bf16(src[g][r][c]); grid (C/32, R/32, NEXP), block (32,8)
__global__ void k_transpose_cvt(const float* __restrict__ src,
                                __hip_bfloat16* __restrict__ dst, int R, int C) {
  __shared__ float tile[32][33];
  int g = blockIdx.z;
  const float* S = src + (size_t)g * R * C;
  __hip_bfloat16* D = dst + (size_t)g * R * C;
  int c0 = blockIdx.x << 5, r0 = blockIdx.y << 5;
  int tx = threadIdx.x, ty = threadIdx.y;
#pragma unroll
  for (int i = 0; i < 4; ++i) {
    int r = ty + i * 8;
    tile[r][tx] = S[(size_t)(r0 + r) * C + c0 + tx];
  }
  __syncthreads();
#pragma unroll
  for (int i = 0; i < 4; ++i) {
    int c = ty + i * 8;
    D[(size_t)(c0 + c) * R + r0 + tx] = __float2bfloat16(tile[tx][c]);
  }
}

__device__ __forceinline__ f32x4 mfma16(s16x8 a, s16x8 b, f32x4 c) {
  asm("v_mfma_f32_16x16x32_bf16 %0, %1, %2, %0" : "+v"(c) : "v"(a), "v"(b));
  return c;
}

// Grouped GEMM, 128x128 tile, BK=64, 4 waves each computing [64,64].
// MODE 1: A = xb rows gathered via perm (K=512), B = W1t [f][h],
//         out = relu(acc+B1) -> Hws bf16 packed rows.
// MODE 2: A = Hws packed rows (K=2048), B = W2t [h][f],
//         out = acc+B2 -> d_out fp32 scattered via perm.
template <int MODE>
__global__ __launch_bounds__(256, 2)
void k_gemm(const int* __restrict__ hdr, const int* __restrict__ perm,
            const __hip_bfloat16* __restrict__ Asrc,
            const __hip_bfloat16* __restrict__ Bsrc,
            const float* __restrict__ bias,
            __hip_bfloat16* __restrict__ Hout, float* __restrict__ Yout) {
  constexpr int K   = (MODE == 1) ? HDIM : FDIM;
  constexpr int LDA = (MODE == 1) ? HDIM : FDIM;
  constexpr int LDB = (MODE == 1) ? HDIM : FDIM;
  constexpr int NT  = (MODE == 1) ? FDIM / 128 : HDIM / 128;
  constexpr int NF  = (MODE == 1) ? FDIM : HDIM;  // B rows / bias len per expert
  const int* tb = hdr + ((MODE == 1) ? 13 : 18);
  const int total = tb[4];

  __shared__ s16x8 AsV[1024];  // 128 rows x 128B
  __shared__ s16x8 BsV[1024];
  char* As = (char*)AsV;
  char* Bs = (char*)BsV;

  const int tid = threadIdx.x, lane = tid & 63, wv = tid >> 6;
  const int wm = (wv >> 1) << 6, wn = (wv & 1) << 6;
  const int sr = tid >> 1, sh = tid & 1;     // staging: row, half
  const int sw = (sr & 7) << 4;              // write-side XOR swizzle
  const int l15 = lane & 15, lq = lane >> 4;

  for (int w = blockIdx.x; w < total; w += gridDim.x) {
    int g = 0;
    while (tb[g + 1] <= w) ++g;
    const int local = w - tb[g];
    const int mt = local / NT, nt = local % NT;
    const int cnt = hdr[g], off = hdr[8 + g];
    int nrows = cnt - (mt << 7);
    nrows = nrows > 128 ? 128 : nrows;

    const __hip_bfloat16* arow = nullptr;
    if (sr < nrows) {
      const int tok = (MODE == 1) ? perm[off + (mt << 7) + sr]
                                  : (off + (mt << 7) + sr);
      arow = Asrc + (size_t)tok * LDA;
    }
    const __hip_bfloat16* brow =
        Bsrc + ((size_t)g * NF + (nt << 7) + sr) * LDB;

    f32x4 acc[4][4];
    const f32x4 fz = {0.f, 0.f, 0.f, 0.f};
#pragma unroll
    for (int m = 0; m < 4; ++m)
#pragma unroll
      for (int n = 0; n < 4; ++n) acc[m][n] = fz;

    for (int k0 = 0; k0 < K; k0 += 64) {
      __syncthreads();
      {  // stage A
        s16x8 v0, v1, v2, v3;
        if (arow) {
          const s16x8* p = (const s16x8*)(arow + k0 + (sh << 5));
          v0 = p[0]; v1 = p[1]; v2 = p[2]; v3 = p[3];
        } else {
          const s16x8 z = {0, 0, 0, 0, 0, 0, 0, 0};
          v0 = z; v1 = z; v2 = z; v3 = z;
        }
        char* rb = As + (sr << 7);
        const int cb = sh << 6;
        *(s16x8*)(rb + ((cb + 0) ^ sw)) = v0;
        *(s16x8*)(rb + ((cb + 16) ^ sw)) = v1;
        *(s16x8*)(rb + ((cb + 32) ^ sw)) = v2;
        *(s16x8*)(rb + ((cb + 48) ^ sw)) = v3;
      }
      {  // stage B (always in-bounds)
        const s16x8* p = (const s16x8*)(brow + k0 + (sh << 5));
        s16x8 v0 = p[0], v1 = p[1], v2 = p[2], v3 = p[3];
        char* rb = Bs + (sr << 7);
        const int cb = sh << 6;
        *(s16x8*)(rb + ((cb + 0) ^ sw)) = v0;
        *(s16x8*)(rb + ((cb + 16) ^ sw)) = v1;
        *(s16x8*)(rb + ((cb + 32) ^ sw)) = v2;
        *(s16x8*)(rb + ((cb + 48) ^ sw)) = v3;
      }
      __syncthreads();
#pragma unroll
      for (int kk = 0; kk < 2; ++kk) {
        const int kb = (kk << 6) + (lq << 4);
        s16x8 a[4], b[4];
#pragma unroll
        for (int m = 0; m < 4; ++m) {
          const int row = wm + (m << 4) + l15;
          a[m] = *(const s16x8*)(As + (row << 7) + (kb ^ ((row & 7) << 4)));
        }
#pragma unroll
        for (int n = 0; n < 4; ++n) {
          const int row = wn + (n << 4) + l15;
          b[n] = *(const s16x8*)(Bs + (row << 7) + (kb ^ ((row & 7) << 4)));
        }
#pragma unroll
        for (int m = 0; m < 4; ++m)
#pragma unroll
          for (int n = 0; n < 4; ++n)
            acc[m][n] = mfma16(a[m], b[n], acc[m][n]);
      }
    }
    asm volatile("s_nop 7\ns_nop 7\ns_nop 7");  // MFMA->VALU read hazard guard

    const int rq = lq << 2;
#pragma unroll
    for (int n = 0; n < 4; ++n) {
      const int ncol = (nt << 7) + wn + (n << 4) + l15;
      const float bv = bias[g * NF + ncol];
#pragma unroll
      for (int m = 0; m < 4; ++m) {
#pragma unroll
        for (int j = 0; j < 4; ++j) {
          const int rl = wm + (m << 4) + rq + j;
          if (rl < nrows) {
            float v = acc[m][n][j] + bv;
            if constexpr (MODE == 1) {
              v = v > 0.f ? v : 0.f;
              Hout[((size_t)(off + (mt << 7) + rl) << 11) + ncol] =
                  __float2bfloat16(v);
            } else {
              const int tok = perm[off + (mt << 7) + rl];
              Yout[((size_t)tok << 9) + ncol] = v;
            }
          }
        }
      }
    }
  }
}

extern "C" void kernel_launch(void* const* d_in, const int* in_sizes, int n_in,
                              void* d_out, int out_size, void* d_ws,
                              size_t ws_size, hipStream_t stream) {
  const float* x    = (const float*)d_in[0];
  const int* b_seq  = (const int*)d_in[1];
  const float* W1   = (const float*)d_in[2];
  const float* B1   = (const float*)d_in[3];
  const float* W2   = (const float*)d_in[4];
  const float* B2   = (const float*)d_in[5];
  float* out        = (float*)d_out;

  char* ws = (char*)d_ws;
  int* hdr  = (int*)ws;                       // 1 KB header
  int* perm = (int*)(ws + 1024);              // 64 KB
  __hip_bfloat16* xb  = (__hip_bfloat16*)(ws + 66560);
  __hip_bfloat16* W1t = xb + (size_t)NTOK * HDIM;          // [4][2048][512]
  __hip_bfloat16* W2t = W1t + (size_t)NEXP * FDIM * HDIM;  // [4][512][2048]
  __hip_bfloat16* Hws = W2t + (size_t)NEXP * HDIM * FDIM;  // [16384][2048]

  const int n4 = NTOK * HDIM / 4;  // also out float4 count

  k_init<<<2048, 256, 0, stream>>>((float4*)out, n4, hdr);
  k_count<<<NTOK / 256, 256, 0, stream>>>(b_seq, hdr);
  k_scan<<<1, 64, 0, stream>>>(hdr);
  k_fill<<<NTOK / 256, 256, 0, stream>>>(b_seq, hdr, perm);
  k_cvt_x<<<2048, 256, 0, stream>>>(x, xb, n4);
  k_transpose_cvt<<<dim3(FDIM / 32, HDIM / 32, NEXP), dim3(32, 8), 0, stream>>>(
      W1, W1t, HDIM, FDIM);
  k_transpose_cvt<<<dim3(HDIM / 32, FDIM / 32, NEXP), dim3(32, 8), 0, stream>>>(
      W2, W2t, FDIM, HDIM);
  k_gemm<1><<<2048, 256, 0, stream>>>(hdr, perm, xb, W1t, B1, Hws, nullptr);
  k_gemm<2><<<512, 256, 0, stream>>>(hdr, perm, Hws, W2t, B2, nullptr, out);
}

// Round 2
// 225.750 us; speedup vs baseline: 1.3566x; 1.3566x over previous
//
#include <hip/hip_runtime.h>
#include <hip/hip_bf16.h>

// ---------------------------------------------------------------------------
// BehaviorSpecificPFF: token-routed 4-expert FFN.
//   y[tok] = relu(x[tok] @ W1[g] + B1[g]) @ W2[g] + B2[g],  g = b_seq[tok]-1
//   b_seq==0 -> zeros.
// Round 2: GEMM staging via global_load_lds (width=16) with pre-swizzled
// per-lane global source; fused init/cvt and count/scan kernels.
// ---------------------------------------------------------------------------

typedef short s16x8 __attribute__((ext_vector_type(8)));
typedef float f32x4 __attribute__((ext_vector_type(4)));

#define NTOK   16384
#define HDIM   512
#define FDIM   2048
#define NEXP   4

// ---- header layout (ints) in ws ----
// [0..3]  counts per expert
// [4..7]  cursors (fill)
// [8..12] token offsets (exclusive prefix, [12]=total)
// [13..17] gemm1 tile bases ([17]=total tiles)
// [18..22] gemm2 tile bases ([22]=total tiles)

__global__ void k_init_cvt(const float* __restrict__ x,
                           __hip_bfloat16* __restrict__ xb,
                           float4* __restrict__ out, int n4,
                           int* __restrict__ hdr, float4* __restrict__ zp) {
  if (blockIdx.x == 0 && threadIdx.x < 32) hdr[threadIdx.x] = 0;
  float4 z; z.x = z.y = z.z = z.w = 0.f;
  int zb = (int)blockIdx.x - 1;
  if (zb >= 0 && zb < 2) zp[zb * 256 + threadIdx.x] = z;  // 8KB zero slab
  union { __hip_bfloat16 b[4]; uint2 u; } t;
  for (int i = blockIdx.x * blockDim.x + threadIdx.x; i < n4;
       i += gridDim.x * blockDim.x) {
    out[i] = z;
    float4 v = ((const float4*)x)[i];
    t.b[0] = __float2bfloat16(v.x);
    t.b[1] = __float2bfloat16(v.y);
    t.b[2] = __float2bfloat16(v.z);
    t.b[3] = __float2bfloat16(v.w);
    ((uint2*)xb)[i] = t.u;
  }
}

__global__ void k_count_scan(const int* __restrict__ b_seq,
                             int* __restrict__ hdr) {
  __shared__ int cnt[4];
  if (threadIdx.x < 4) cnt[threadIdx.x] = 0;
  __syncthreads();
  int c0 = 0, c1 = 0, c2 = 0, c3 = 0;
  for (int i = threadIdx.x; i < NTOK; i += 256) {
    int g = b_seq[i];
    if (g == 1) ++c0;
    else if (g == 2) ++c1;
    else if (g == 3) ++c2;
    else if (g == 4) ++c3;
  }
  if (c0) atomicAdd(&cnt[0], c0);
  if (c1) atomicAdd(&cnt[1], c1);
  if (c2) atomicAdd(&cnt[2], c2);
  if (c3) atomicAdd(&cnt[3], c3);
  __syncthreads();
  if (threadIdx.x == 0) {
    int off = 0, b1 = 0, b2 = 0;
    for (int g = 0; g < 4; ++g) {
      int c = cnt[g];
      hdr[g] = c;
      hdr[8 + g] = off;
      hdr[4 + g] = off;   // cursor
      hdr[13 + g] = b1;
      hdr[18 + g] = b2;
      int mt = (c + 127) >> 7;
      off += c;
      b1 += mt * (FDIM / 128);
      b2 += mt * (HDIM / 128);
    }
    hdr[12] = off; hdr[17] = b1; hdr[22] = b2;
  }
}

__global__ void k_fill(const int* __restrict__ b_seq, int* __restrict__ hdr,
                       int* __restrict__ perm) {
  int i = blockIdx.x * blockDim.x + threadIdx.x;
  int g = b_seq[i];
  if (g > 0) {
    int p = atomicAdd(&hdr[4 + g - 1], 1);
    perm[p] = i;
  }
}

// dst[g][c][r] = bf16(src[g][r][c]); grid (C/32, R/32, NEXP), block (32,8)
__global__ void k_transpose_cvt(const float* __restrict__ src,
                                __hip_bfloat16* __restrict__ dst, int R, int C) {
  __shared__ float tile[32][33];
  int g = blockIdx.z;
  const float* S = src + (size_t)g * R * C;
  __hip_bfloat16* D = dst + (size_t)g * R * C;
  int c0 = blockIdx.x << 5, r0 = blockIdx.y << 5;
  int tx = threadIdx.x, ty = threadIdx.y;
#pragma unroll
  for (int i = 0; i < 4; ++i) {
    int r = ty + i * 8;
    tile[r][tx] = S[(size_t)(r0 + r) * C + c0 + tx];
  }
  __syncthreads();
#pragma unroll
  for (int i = 0; i < 4; ++i) {
    int c = ty + i * 8;
    D[(size_t)(c0 + c) * R + r0 + tx] = __float2bfloat16(tile[tx][c]);
  }
}

__device__ __forceinline__ f32x4 mfma16(s16x8 a, s16x8 b, f32x4 c) {
  asm("v_mfma_f32_16x16x32_bf16 %0, %1, %2, %0" : "+v"(c) : "v"(a), "v"(b));
  return c;
}

__device__ __forceinline__ void gload16(const void* g, void* lds) {
  __builtin_amdgcn_global_load_lds(
      (const __attribute__((address_space(1))) unsigned int*)g,
      (__attribute__((address_space(3))) unsigned int*)lds, 16, 0, 0);
}

// Grouped GEMM, 128x128 tile, BK=64, 4 waves each computing [64,64].
// Staging: global_load_lds dwordx4, LDS linear [row][chunk], source address
// pre-swizzled chunk = c8 ^ (row&7); fragment reads use kb ^ ((row&7)<<4).
// MODE 1: A = xb rows gathered via perm (K=512), B = W1t [f][h],
//         out = relu(acc+B1) -> Hws bf16 packed rows.
// MODE 2: A = Hws packed rows (K=2048), B = W2t [h][f],
//         out = acc+B2 -> d_out fp32 scattered via perm.
template <int MODE>
__global__ __launch_bounds__(256, 2)
void k_gemm(const int* __restrict__ hdr, const int* __restrict__ perm,
            const __hip_bfloat16* __restrict__ Asrc,
            const __hip_bfloat16* __restrict__ Bsrc,
            const float* __restrict__ bias,
            const __hip_bfloat16* __restrict__ zp,
            __hip_bfloat16* __restrict__ Hout, float* __restrict__ Yout) {
  constexpr int K   = (MODE == 1) ? HDIM : FDIM;
  constexpr int LDA = (MODE == 1) ? HDIM : FDIM;
  constexpr int LDB = (MODE == 1) ? HDIM : FDIM;
  constexpr int NT  = (MODE == 1) ? FDIM / 128 : HDIM / 128;
  constexpr int NF  = (MODE == 1) ? FDIM : HDIM;
  const int* tb = hdr + ((MODE == 1) ? 13 : 18);
  const int total = tb[4];

  __shared__ s16x8 AsV[1024];  // 16KB: 128 rows x 128B (BK=64 bf16)
  __shared__ s16x8 BsV[1024];
  char* As = (char*)AsV;
  char* Bs = (char*)BsV;

  const int tid = threadIdx.x, lane = tid & 63, wv = tid >> 6;
  const int wm = (wv >> 1) << 6, wn = (wv & 1) << 6;
  const int l15 = lane & 15, lq = lane >> 4;
  const int sw2 = (l15 & 7) << 4;            // read-side swizzle
  const int c8 = lane & 7, rsub = lane >> 3; // staging lane -> chunk,row

  for (int w = blockIdx.x; w < total; w += gridDim.x) {
    int g = 0;
    while (tb[g + 1] <= w) ++g;
    const int local = w - tb[g];
    const int mt = local / NT, nt = local % NT;
    const int cnt = hdr[g], off = hdr[8 + g];
    int nrows = cnt - (mt << 7);
    nrows = nrows > 128 ? 128 : nrows;

    // per-instruction source pointers (advance by 64 elems per K-step)
    const __hip_bfloat16* ap[4];
    const __hip_bfloat16* bp[4];
#pragma unroll
    for (int i = 0; i < 4; ++i) {
      const int r = (i << 5) + (wv << 3) + rsub;
      const int co = (c8 ^ (r & 7)) << 3;  // swizzled chunk, elem offset
      if (MODE == 1) {
        if (r < nrows) {
          const int tok = perm[off + (mt << 7) + r];
          ap[i] = Asrc + (size_t)tok * LDA + co;
        } else {
          ap[i] = zp + (c8 << 3);  // zero slab (walks k0, slab is 8KB)
        }
      } else {
        ap[i] = Asrc + (size_t)(off + (mt << 7) + r) * LDA + co;
      }
      bp[i] = Bsrc + ((size_t)g * NF + (nt << 7) + r) * LDB + co;
    }

    f32x4 acc[4][4];
    const f32x4 fz = {0.f, 0.f, 0.f, 0.f};
#pragma unroll
    for (int m = 0; m < 4; ++m)
#pragma unroll
      for (int n = 0; n < 4; ++n) acc[m][n] = fz;

    for (int k0 = 0; k0 < K; k0 += 64) {
      __syncthreads();  // prev MFMA reads done before overwrite
#pragma unroll
      for (int i = 0; i < 4; ++i) {
        const int lo = (i << 12) + (wv << 10);  // wave-uniform LDS base
        gload16(ap[i], As + lo);
        gload16(bp[i], Bs + lo);
        ap[i] += 64;
        bp[i] += 64;
      }
      __syncthreads();  // drains vmcnt(0): staged data visible
#pragma unroll
      for (int kk = 0; kk < 2; ++kk) {
        const int kb = (kk << 6) + (lq << 4);
        s16x8 a[4], b[4];
#pragma unroll
        for (int m = 0; m < 4; ++m) {
          const int row = wm + (m << 4) + l15;
          a[m] = *(const s16x8*)(As + (row << 7) + (kb ^ sw2));
        }
#pragma unroll
        for (int n = 0; n < 4; ++n) {
          const int row = wn + (n << 4) + l15;
          b[n] = *(const s16x8*)(Bs + (row << 7) + (kb ^ sw2));
        }
#pragma unroll
        for (int m = 0; m < 4; ++m)
#pragma unroll
          for (int n = 0; n < 4; ++n)
            acc[m][n] = mfma16(a[m], b[n], acc[m][n]);
      }
    }
    asm volatile("s_nop 7\ns_nop 7\ns_nop 7");  // MFMA->VALU hazard guard

    const int rq = lq << 2;
#pragma unroll
    for (int n = 0; n < 4; ++n) {
      const int ncol = (nt << 7) + wn + (n << 4) + l15;
      const float bv = bias[g * NF + ncol];
#pragma unroll
      for (int m = 0; m < 4; ++m) {
#pragma unroll
        for (int j = 0; j < 4; ++j) {
          const int rl = wm + (m << 4) + rq + j;
          if (rl < nrows) {
            float v = acc[m][n][j] + bv;
            if constexpr (MODE == 1) {
              v = v > 0.f ? v : 0.f;
              Hout[((size_t)(off + (mt << 7) + rl) << 11) + ncol] =
                  __float2bfloat16(v);
            } else {
              const int tok = perm[off + (mt << 7) + rl];
              Yout[((size_t)tok << 9) + ncol] = v;
            }
          }
        }
      }
    }
  }
}

extern "C" void kernel_launch(void* const* d_in, const int* in_sizes, int n_in,
                              void* d_out, int out_size, void* d_ws,
                              size_t ws_size, hipStream_t stream) {
  const float* x    = (const float*)d_in[0];
  const int* b_seq  = (const int*)d_in[1];
  const float* W1   = (const float*)d_in[2];
  const float* B1   = (const float*)d_in[3];
  const float* W2   = (const float*)d_in[4];
  const float* B2   = (const float*)d_in[5];
  float* out        = (float*)d_out;

  char* ws = (char*)d_ws;
  int* hdr  = (int*)ws;                         // 1 KB header
  int* perm = (int*)(ws + 1024);                // 64 KB
  __hip_bfloat16* zp = (__hip_bfloat16*)(ws + 66560);       // 8 KB zeros
  __hip_bfloat16* xb = zp + 4096;
  __hip_bfloat16* W1t = xb + (size_t)NTOK * HDIM;           // [4][2048][512]
  __hip_bfloat16* W2t = W1t + (size_t)NEXP * FDIM * HDIM;   // [4][512][2048]
  __hip_bfloat16* Hws = W2t + (size_t)NEXP * HDIM * FDIM;   // [16384][2048]

  const int n4 = NTOK * HDIM / 4;

  k_init_cvt<<<2048, 256, 0, stream>>>(x, xb, (float4*)out, n4, hdr,
                                       (float4*)zp);
  k_count_scan<<<1, 256, 0, stream>>>(b_seq, hdr);
  k_fill<<<NTOK / 256, 256, 0, stream>>>(b_seq, hdr, perm);
  k_transpose_cvt<<<dim3(FDIM / 32, HDIM / 32, NEXP), dim3(32, 8), 0, stream>>>(
      W1, W1t, HDIM, FDIM);
  k_transpose_cvt<<<dim3(HDIM / 32, FDIM / 32, NEXP), dim3(32, 8), 0, stream>>>(
      W2, W2t, FDIM, HDIM);
  k_gemm<1><<<2048, 256, 0, stream>>>(hdr, perm, xb, W1t, B1, zp, Hws, nullptr);
  k_gemm<2><<<512, 256, 0, stream>>>(hdr, perm, Hws, W2t, B2, zp, nullptr, out);
}

// Round 3
// 153.050 us; speedup vs baseline: 2.0010x; 1.4750x over previous
//
#include <hip/hip_runtime.h>
#include <hip/hip_bf16.h>

// ---------------------------------------------------------------------------
// BehaviorSpecificPFF: token-routed 4-expert FFN.
//   y[tok] = relu(x[tok] @ W1[g] + B1[g]) @ W2[g] + B2[g],  g = b_seq[tok]-1
//   b_seq==0 -> zeros.
// Round 3: de-contend routing atomics (LDS-aggregated k_fill, wide
// k_count_scan). GEMM path unchanged from round 2 (global_load_lds staging,
// pre-swizzled source, XOR-swizzled fragment reads).
// ---------------------------------------------------------------------------

typedef short s16x8 __attribute__((ext_vector_type(8)));
typedef float f32x4 __attribute__((ext_vector_type(4)));

#define NTOK   16384
#define HDIM   512
#define FDIM   2048
#define NEXP   4

// ---- header layout (ints) in ws ----
// [0..3]  counts per expert
// [4..7]  cursors (fill)
// [8..12] token offsets (exclusive prefix, [12]=total)
// [13..17] gemm1 tile bases ([17]=total tiles)
// [18..22] gemm2 tile bases ([22]=total tiles)

__global__ void k_init_cvt(const float* __restrict__ x,
                           __hip_bfloat16* __restrict__ xb,
                           float4* __restrict__ out, int n4,
                           int* __restrict__ hdr, float4* __restrict__ zp) {
  if (blockIdx.x == 0 && threadIdx.x < 32) hdr[threadIdx.x] = 0;
  float4 z; z.x = z.y = z.z = z.w = 0.f;
  int zb = (int)blockIdx.x - 1;
  if (zb >= 0 && zb < 2) zp[zb * 256 + threadIdx.x] = z;  // 8KB zero slab
  union { __hip_bfloat16 b[4]; uint2 u; } t;
  for (int i = blockIdx.x * blockDim.x + threadIdx.x; i < n4;
       i += gridDim.x * blockDim.x) {
    out[i] = z;
    float4 v = ((const float4*)x)[i];
    t.b[0] = __float2bfloat16(v.x);
    t.b[1] = __float2bfloat16(v.y);
    t.b[2] = __float2bfloat16(v.z);
    t.b[3] = __float2bfloat16(v.w);
    ((uint2*)xb)[i] = t.u;
  }
}

__global__ void k_count_scan(const int4* __restrict__ b4,
                             int* __restrict__ hdr) {
  __shared__ int cnt[4];
  if (threadIdx.x < 4) cnt[threadIdx.x] = 0;
  __syncthreads();
  int c0 = 0, c1 = 0, c2 = 0, c3 = 0;
  for (int i = threadIdx.x; i < NTOK / 4; i += 1024) {
    int4 v = b4[i];
    c0 += (v.x == 1) + (v.y == 1) + (v.z == 1) + (v.w == 1);
    c1 += (v.x == 2) + (v.y == 2) + (v.z == 2) + (v.w == 2);
    c2 += (v.x == 3) + (v.y == 3) + (v.z == 3) + (v.w == 3);
    c3 += (v.x == 4) + (v.y == 4) + (v.z == 4) + (v.w == 4);
  }
  if (c0) atomicAdd(&cnt[0], c0);
  if (c1) atomicAdd(&cnt[1], c1);
  if (c2) atomicAdd(&cnt[2], c2);
  if (c3) atomicAdd(&cnt[3], c3);
  __syncthreads();
  if (threadIdx.x == 0) {
    int off = 0, b1 = 0, b2 = 0;
    for (int g = 0; g < 4; ++g) {
      int c = cnt[g];
      hdr[g] = c;
      hdr[8 + g] = off;
      hdr[4 + g] = off;   // cursor
      hdr[13 + g] = b1;
      hdr[18 + g] = b2;
      int mt = (c + 127) >> 7;
      off += c;
      b1 += mt * (FDIM / 128);
      b2 += mt * (HDIM / 128);
    }
    hdr[12] = off; hdr[17] = b1; hdr[22] = b2;
  }
}

// LDS-aggregated fill: intra-block rank via LDS atomics, one global atomic
// per (block, expert). Perm order is scheduler-dependent but the final
// output is invariant to row placement, so the result is deterministic.
__global__ void k_fill(const int* __restrict__ b_seq, int* __restrict__ hdr,
                       int* __restrict__ perm) {
  __shared__ int lcnt[4], base[4];
  const int tid = threadIdx.x;
  if (tid < 4) lcnt[tid] = 0;
  __syncthreads();
  const int i = blockIdx.x * 256 + tid;
  const int g = b_seq[i];
  int r = -1;
  if (g > 0) r = atomicAdd(&lcnt[g - 1], 1);
  __syncthreads();
  if (tid < 4) {
    int c = lcnt[tid];
    base[tid] = c ? atomicAdd(&hdr[4 + tid], c) : 0;
  }
  __syncthreads();
  if (g > 0) perm[base[g - 1] + r] = i;
}

// dst[g][c][r] = bf16(src[g][r][c]); grid (C/32, R/32, NEXP), block (32,8)
__global__ void k_transpose_cvt(const float* __restrict__ src,
                                __hip_bfloat16* __restrict__ dst, int R, int C) {
  __shared__ float tile[32][33];
  int g = blockIdx.z;
  const float* S = src + (size_t)g * R * C;
  __hip_bfloat16* D = dst + (size_t)g * R * C;
  int c0 = blockIdx.x << 5, r0 = blockIdx.y << 5;
  int tx = threadIdx.x, ty = threadIdx.y;
#pragma unroll
  for (int i = 0; i < 4; ++i) {
    int r = ty + i * 8;
    tile[r][tx] = S[(size_t)(r0 + r) * C + c0 + tx];
  }
  __syncthreads();
#pragma unroll
  for (int i = 0; i < 4; ++i) {
    int c = ty + i * 8;
    D[(size_t)(c0 + c) * R + r0 + tx] = __float2bfloat16(tile[tx][c]);
  }
}

__device__ __forceinline__ f32x4 mfma16(s16x8 a, s16x8 b, f32x4 c) {
  asm("v_mfma_f32_16x16x32_bf16 %0, %1, %2, %0" : "+v"(c) : "v"(a), "v"(b));
  return c;
}

__device__ __forceinline__ void gload16(const void* g, void* lds) {
  __builtin_amdgcn_global_load_lds(
      (const __attribute__((address_space(1))) unsigned int*)g,
      (__attribute__((address_space(3))) unsigned int*)lds, 16, 0, 0);
}

// Grouped GEMM, 128x128 tile, BK=64, 4 waves each computing [64,64].
// Staging: global_load_lds dwordx4, LDS linear [row][chunk], source address
// pre-swizzled chunk = c8 ^ (row&7); fragment reads use kb ^ ((row&7)<<4).
// MODE 1: A = xb rows gathered via perm (K=512), B = W1t [f][h],
//         out = relu(acc+B1) -> Hws bf16 packed rows.
// MODE 2: A = Hws packed rows (K=2048), B = W2t [h][f],
//         out = acc+B2 -> d_out fp32 scattered via perm.
template <int MODE>
__global__ __launch_bounds__(256, 2)
void k_gemm(const int* __restrict__ hdr, const int* __restrict__ perm,
            const __hip_bfloat16* __restrict__ Asrc,
            const __hip_bfloat16* __restrict__ Bsrc,
            const float* __restrict__ bias,
            const __hip_bfloat16* __restrict__ zp,
            __hip_bfloat16* __restrict__ Hout, float* __restrict__ Yout) {
  constexpr int K   = (MODE == 1) ? HDIM : FDIM;
  constexpr int LDA = (MODE == 1) ? HDIM : FDIM;
  constexpr int LDB = (MODE == 1) ? HDIM : FDIM;
  constexpr int NT  = (MODE == 1) ? FDIM / 128 : HDIM / 128;
  constexpr int NF  = (MODE == 1) ? FDIM : HDIM;
  const int* tb = hdr + ((MODE == 1) ? 13 : 18);
  const int total = tb[4];

  __shared__ s16x8 AsV[1024];  // 16KB: 128 rows x 128B (BK=64 bf16)
  __shared__ s16x8 BsV[1024];
  char* As = (char*)AsV;
  char* Bs = (char*)BsV;

  const int tid = threadIdx.x, lane = tid & 63, wv = tid >> 6;
  const int wm = (wv >> 1) << 6, wn = (wv & 1) << 6;
  const int l15 = lane & 15, lq = lane >> 4;
  const int sw2 = (l15 & 7) << 4;            // read-side swizzle
  const int c8 = lane & 7, rsub = lane >> 3; // staging lane -> chunk,row

  for (int w = blockIdx.x; w < total; w += gridDim.x) {
    int g = 0;
    while (tb[g + 1] <= w) ++g;
    const int local = w - tb[g];
    const int mt = local / NT, nt = local % NT;
    const int cnt = hdr[g], off = hdr[8 + g];
    int nrows = cnt - (mt << 7);
    nrows = nrows > 128 ? 128 : nrows;

    // per-instruction source pointers (advance by 64 elems per K-step)
    const __hip_bfloat16* ap[4];
    const __hip_bfloat16* bp[4];
#pragma unroll
    for (int i = 0; i < 4; ++i) {
      const int r = (i << 5) + (wv << 3) + rsub;
      const int co = (c8 ^ (r & 7)) << 3;  // swizzled chunk, elem offset
      if (MODE == 1) {
        if (r < nrows) {
          const int tok = perm[off + (mt << 7) + r];
          ap[i] = Asrc + (size_t)tok * LDA + co;
        } else {
          ap[i] = zp + (c8 << 3);  // zero slab (walks k0, slab is 8KB)
        }
      } else {
        ap[i] = Asrc + (size_t)(off + (mt << 7) + r) * LDA + co;
      }
      bp[i] = Bsrc + ((size_t)g * NF + (nt << 7) + r) * LDB + co;
    }

    f32x4 acc[4][4];
    const f32x4 fz = {0.f, 0.f, 0.f, 0.f};
#pragma unroll
    for (int m = 0; m < 4; ++m)
#pragma unroll
      for (int n = 0; n < 4; ++n) acc[m][n] = fz;

    for (int k0 = 0; k0 < K; k0 += 64) {
      __syncthreads();  // prev MFMA reads done before overwrite
#pragma unroll
      for (int i = 0; i < 4; ++i) {
        const int lo = (i << 12) + (wv << 10);  // wave-uniform LDS base
        gload16(ap[i], As + lo);
        gload16(bp[i], Bs + lo);
        ap[i] += 64;
        bp[i] += 64;
      }
      __syncthreads();  // drains vmcnt(0): staged data visible
#pragma unroll
      for (int kk = 0; kk < 2; ++kk) {
        const int kb = (kk << 6) + (lq << 4);
        s16x8 a[4], b[4];
#pragma unroll
        for (int m = 0; m < 4; ++m) {
          const int row = wm + (m << 4) + l15;
          a[m] = *(const s16x8*)(As + (row << 7) + (kb ^ sw2));
        }
#pragma unroll
        for (int n = 0; n < 4; ++n) {
          const int row = wn + (n << 4) + l15;
          b[n] = *(const s16x8*)(Bs + (row << 7) + (kb ^ sw2));
        }
#pragma unroll
        for (int m = 0; m < 4; ++m)
#pragma unroll
          for (int n = 0; n < 4; ++n)
            acc[m][n] = mfma16(a[m], b[n], acc[m][n]);
      }
    }
    asm volatile("s_nop 7\ns_nop 7\ns_nop 7");  // MFMA->VALU hazard guard

    const int rq = lq << 2;
#pragma unroll
    for (int n = 0; n < 4; ++n) {
      const int ncol = (nt << 7) + wn + (n << 4) + l15;
      const float bv = bias[g * NF + ncol];
#pragma unroll
      for (int m = 0; m < 4; ++m) {
#pragma unroll
        for (int j = 0; j < 4; ++j) {
          const int rl = wm + (m << 4) + rq + j;
          if (rl < nrows) {
            float v = acc[m][n][j] + bv;
            if constexpr (MODE == 1) {
              v = v > 0.f ? v : 0.f;
              Hout[((size_t)(off + (mt << 7) + rl) << 11) + ncol] =
                  __float2bfloat16(v);
            } else {
              const int tok = perm[off + (mt << 7) + rl];
              Yout[((size_t)tok << 9) + ncol] = v;
            }
          }
        }
      }
    }
  }
}

extern "C" void kernel_launch(void* const* d_in, const int* in_sizes, int n_in,
                              void* d_out, int out_size, void* d_ws,
                              size_t ws_size, hipStream_t stream) {
  const float* x    = (const float*)d_in[0];
  const int* b_seq  = (const int*)d_in[1];
  const float* W1   = (const float*)d_in[2];
  const float* B1   = (const float*)d_in[3];
  const float* W2   = (const float*)d_in[4];
  const float* B2   = (const float*)d_in[5];
  float* out        = (float*)d_out;

  char* ws = (char*)d_ws;
  int* hdr  = (int*)ws;                         // 1 KB header
  int* perm = (int*)(ws + 1024);                // 64 KB
  __hip_bfloat16* zp = (__hip_bfloat16*)(ws + 66560);       // 8 KB zeros
  __hip_bfloat16* xb = zp + 4096;
  __hip_bfloat16* W1t = xb + (size_t)NTOK * HDIM;           // [4][2048][512]
  __hip_bfloat16* W2t = W1t + (size_t)NEXP * FDIM * HDIM;   // [4][512][2048]
  __hip_bfloat16* Hws = W2t + (size_t)NEXP * HDIM * FDIM;   // [16384][2048]

  const int n4 = NTOK * HDIM / 4;

  k_init_cvt<<<2048, 256, 0, stream>>>(x, xb, (float4*)out, n4, hdr,
                                       (float4*)zp);
  k_count_scan<<<1, 1024, 0, stream>>>((const int4*)b_seq, hdr);
  k_fill<<<NTOK / 256, 256, 0, stream>>>(b_seq, hdr, perm);
  k_transpose_cvt<<<dim3(FDIM / 32, HDIM / 32, NEXP), dim3(32, 8), 0, stream>>>(
      W1, W1t, HDIM, FDIM);
  k_transpose_cvt<<<dim3(HDIM / 32, FDIM / 32, NEXP), dim3(32, 8), 0, stream>>>(
      W2, W2t, FDIM, HDIM);
  k_gemm<1><<<2048, 256, 0, stream>>>(hdr, perm, xb, W1t, B1, zp, Hws, nullptr);
  k_gemm<2><<<512, 256, 0, stream>>>(hdr, perm, Hws, W2t, B2, zp, nullptr, out);
}

// Round 5
// 146.838 us; speedup vs baseline: 2.0857x; 1.0423x over previous
//
#include <hip/hip_runtime.h>
#include <hip/hip_bf16.h>

// ---------------------------------------------------------------------------
// BehaviorSpecificPFF: token-routed 4-expert FFN.
//   y[tok] = relu(x[tok] @ W1[g] + B1[g]) @ W2[g] + B2[g],  g = b_seq[tok]-1
//   b_seq==0 -> zeros.
// Round 5: guide-verified minimal 2-phase pipeline (STAGE(next) -> ds_read ->
// MFMA -> vmcnt(0) -> barrier; count-independent waits). GEMM1 C-tile staged
// through LDS for coalesced 128B H-row stores (round-3 showed 2x write
// amplification from scalar bf16 stores).
// ---------------------------------------------------------------------------

typedef short s16x8 __attribute__((ext_vector_type(8)));
typedef float f32x4 __attribute__((ext_vector_type(4)));

#define NTOK   16384
#define HDIM   512
#define FDIM   2048
#define NEXP   4

// ---- header layout (ints) in ws ----
// [0..3] counts  [4..7] cursors  [8..12] token offsets ([12]=total)
// [13..17] gemm1 tile bases ([17]=total)  [18..22] gemm2 tile bases

__global__ void k_init_cvt(const float* __restrict__ x,
                           const int* __restrict__ b_seq,
                           __hip_bfloat16* __restrict__ xb,
                           float4* __restrict__ out, int n4,
                           int* __restrict__ hdr, float4* __restrict__ zp) {
  if (blockIdx.x == 0 && threadIdx.x < 32) hdr[threadIdx.x] = 0;
  float4 z; z.x = z.y = z.z = z.w = 0.f;
  int zb = (int)blockIdx.x - 1;
  if (zb >= 0 && zb < 2) zp[zb * 256 + threadIdx.x] = z;  // 8KB zero slab
  union { __hip_bfloat16 b[4]; uint2 u; } t;
  for (int i = blockIdx.x * blockDim.x + threadIdx.x; i < n4;
       i += gridDim.x * blockDim.x) {
    // non-pad out rows are fully rewritten by GEMM2 every call; only padding
    // rows need zeros (out float4-row token = i>>7).
    if (b_seq[i >> 7] == 0) out[i] = z;
    float4 v = ((const float4*)x)[i];
    t.b[0] = __float2bfloat16(v.x);
    t.b[1] = __float2bfloat16(v.y);
    t.b[2] = __float2bfloat16(v.z);
    t.b[3] = __float2bfloat16(v.w);
    ((uint2*)xb)[i] = t.u;
  }
}

__global__ void k_count_scan(const int4* __restrict__ b4,
                             int* __restrict__ hdr) {
  __shared__ int cnt[4];
  if (threadIdx.x < 4) cnt[threadIdx.x] = 0;
  __syncthreads();
  int c0 = 0, c1 = 0, c2 = 0, c3 = 0;
  for (int i = threadIdx.x; i < NTOK / 4; i += 1024) {
    int4 v = b4[i];
    c0 += (v.x == 1) + (v.y == 1) + (v.z == 1) + (v.w == 1);
    c1 += (v.x == 2) + (v.y == 2) + (v.z == 2) + (v.w == 2);
    c2 += (v.x == 3) + (v.y == 3) + (v.z == 3) + (v.w == 3);
    c3 += (v.x == 4) + (v.y == 4) + (v.z == 4) + (v.w == 4);
  }
  if (c0) atomicAdd(&cnt[0], c0);
  if (c1) atomicAdd(&cnt[1], c1);
  if (c2) atomicAdd(&cnt[2], c2);
  if (c3) atomicAdd(&cnt[3], c3);
  __syncthreads();
  if (threadIdx.x == 0) {
    int off = 0, b1 = 0, b2 = 0;
    for (int g = 0; g < 4; ++g) {
      int c = cnt[g];
      hdr[g] = c;
      hdr[8 + g] = off;
      hdr[4 + g] = off;   // cursor
      hdr[13 + g] = b1;
      hdr[18 + g] = b2;
      int mt = (c + 127) >> 7;
      off += c;
      b1 += mt * (FDIM / 128);
      b2 += mt * (HDIM / 128);
    }
    hdr[12] = off; hdr[17] = b1; hdr[22] = b2;
  }
}

// LDS-aggregated fill: one global atomic per (block, expert).
__global__ void k_fill(const int* __restrict__ b_seq, int* __restrict__ hdr,
                       int* __restrict__ perm) {
  __shared__ int lcnt[4], base[4];
  const int tid = threadIdx.x;
  if (tid < 4) lcnt[tid] = 0;
  __syncthreads();
  const int i = blockIdx.x * 256 + tid;
  const int g = b_seq[i];
  int r = -1;
  if (g > 0) r = atomicAdd(&lcnt[g - 1], 1);
  __syncthreads();
  if (tid < 4) {
    int c = lcnt[tid];
    base[tid] = c ? atomicAdd(&hdr[4 + tid], c) : 0;
  }
  __syncthreads();
  if (g > 0) perm[base[g - 1] + r] = i;
}

// dst[g][c][r] = bf16(src[g][r][c]); grid (C/32, R/32, NEXP), block (32,8)
__global__ void k_transpose_cvt(const float* __restrict__ src,
                                __hip_bfloat16* __restrict__ dst, int R, int C) {
  __shared__ float tile[32][33];
  int g = blockIdx.z;
  const float* S = src + (size_t)g * R * C;
  __hip_bfloat16* D = dst + (size_t)g * R * C;
  int c0 = blockIdx.x << 5, r0 = blockIdx.y << 5;
  int tx = threadIdx.x, ty = threadIdx.y;
#pragma unroll
  for (int i = 0; i < 4; ++i) {
    int r = ty + i * 8;
    tile[r][tx] = S[(size_t)(r0 + r) * C + c0 + tx];
  }
  __syncthreads();
#pragma unroll
  for (int i = 0; i < 4; ++i) {
    int c = ty + i * 8;
    D[(size_t)(c0 + c) * R + r0 + tx] = __float2bfloat16(tile[tx][c]);
  }
}

__device__ __forceinline__ f32x4 mfma16(s16x8 a, s16x8 b, f32x4 c) {
  asm("v_mfma_f32_16x16x32_bf16 %0, %1, %2, %0" : "+v"(c) : "v"(a), "v"(b));
  return c;
}

__device__ __forceinline__ void gload16(const void* g, void* lds) {
  __builtin_amdgcn_global_load_lds(
      (const __attribute__((address_space(1))) unsigned int*)g,
      (__attribute__((address_space(3))) unsigned int*)lds, 16, 0, 0);
}

// Grouped GEMM, 128x128 tile, BK=64, 4 waves each computing [64,64].
// Verified 2-phase recipe: STAGE(next buf) -> ds_read(cur) -> MFMA ->
// vmcnt(0) -> s_barrier. Count-independent waits; load latency hides under
// the MFMA cluster.
// MODE 1: A = xb gathered via perm (K=512), B = W1t; relu+bias; C-tile staged
//         in LDS then coalesced 128B/row stores to Hws (bf16 packed).
// MODE 2: A = Hws packed (K=2048), B = W2t; +bias; fp32 scatter to d_out.
template <int MODE>
__global__ __launch_bounds__(256, 2)
void k_gemm(const int* __restrict__ hdr, const int* __restrict__ perm,
            const __hip_bfloat16* __restrict__ Asrc,
            const __hip_bfloat16* __restrict__ Bsrc,
            const float* __restrict__ bias,
            const __hip_bfloat16* __restrict__ zp,
            __hip_bfloat16* __restrict__ Hout, float* __restrict__ Yout) {
  constexpr int K   = (MODE == 1) ? HDIM : FDIM;
  constexpr int NS  = K / 64;                     // K-steps per tile
  constexpr int LDA = (MODE == 1) ? HDIM : FDIM;
  constexpr int LDB = (MODE == 1) ? HDIM : FDIM;
  constexpr int NT  = (MODE == 1) ? FDIM / 128 : HDIM / 128;
  constexpr int NF  = (MODE == 1) ? FDIM : HDIM;
  const int* tb = hdr + ((MODE == 1) ? 13 : 18);
  const int total = tb[4];

  __shared__ char LDS[65536];       // As dbuf 32KB | Bs dbuf 32KB
  char* As = LDS;
  char* Bs = LDS + 32768;

  const int tid = threadIdx.x, lane = tid & 63, wv = tid >> 6;
  const int wm = (wv >> 1) << 6, wn = (wv & 1) << 6;
  const int l15 = lane & 15, lq = lane >> 4;
  const int sw2 = (l15 & 7) << 4;            // read-side swizzle
  const int c8 = lane & 7, rsub = lane >> 3; // staging lane -> chunk,row

  for (int w = blockIdx.x; w < total; w += gridDim.x) {
    int g = 0;
    while (tb[g + 1] <= w) ++g;
    const int local = w - tb[g];
    const int mt = local / NT, nt = local % NT;
    const int cnt = hdr[g], off = hdr[8 + g];
    int nrows = cnt - (mt << 7);
    nrows = nrows > 128 ? 128 : nrows;

    const __hip_bfloat16* ap[4];
    const __hip_bfloat16* bp[4];
#pragma unroll
    for (int i = 0; i < 4; ++i) {
      const int r = (i << 5) + (wv << 3) + rsub;
      const int co = (c8 ^ (r & 7)) << 3;  // swizzled-chunk elem offset
      if (MODE == 1) {
        if (r < nrows) {
          const int tok = perm[off + (mt << 7) + r];
          ap[i] = Asrc + (size_t)tok * LDA + co;
        } else {
          ap[i] = zp + (c8 << 3);  // zero slab (walks k0, slab is 8KB)
        }
      } else {
        ap[i] = Asrc + (size_t)(off + (mt << 7) + r) * LDA + co;
      }
      bp[i] = Bsrc + ((size_t)g * NF + (nt << 7) + r) * LDB + co;
    }

    f32x4 acc[4][4];
    const f32x4 fz = {0.f, 0.f, 0.f, 0.f};
#pragma unroll
    for (int m = 0; m < 4; ++m)
#pragma unroll
      for (int n = 0; n < 4; ++n) acc[m][n] = fz;

    auto STAGE = [&](int bo) {
#pragma unroll
      for (int i = 0; i < 4; ++i) {
        const int lo = bo + (i << 12) + (wv << 10);  // wave-uniform LDS dest
        gload16(ap[i], As + lo);
        gload16(bp[i], Bs + lo);
        ap[i] += 64;
        bp[i] += 64;
      }
    };
    auto COMPUTE = [&](int bo) {
      s16x8 a[2][4], b[2][4];
#pragma unroll
      for (int kk = 0; kk < 2; ++kk) {
        const int kb = (kk << 6) + (lq << 4);
#pragma unroll
        for (int m = 0; m < 4; ++m) {
          const int row = wm + (m << 4) + l15;
          a[kk][m] = *(const s16x8*)(As + bo + (row << 7) + (kb ^ sw2));
        }
#pragma unroll
        for (int n = 0; n < 4; ++n) {
          const int row = wn + (n << 4) + l15;
          b[kk][n] = *(const s16x8*)(Bs + bo + (row << 7) + (kb ^ sw2));
        }
      }
#pragma unroll
      for (int kk = 0; kk < 2; ++kk)
#pragma unroll
        for (int m = 0; m < 4; ++m)
#pragma unroll
          for (int n = 0; n < 4; ++n)
            acc[m][n] = mfma16(a[kk][m], b[kk][n], acc[m][n]);
    };

    // prologue: stage tile 0, drain, sync
    STAGE(0);
    asm volatile("s_waitcnt vmcnt(0)" ::: "memory");
    __builtin_amdgcn_s_barrier();
    asm volatile("" ::: "memory");

    int bo = 0;
    for (int s = 0; s < NS; ++s) {
      if (s + 1 < NS) STAGE(bo ^ 16384);   // issue next K-step loads
      COMPUTE(bo);                          // ds_read + MFMA (deps ordered)
      asm volatile("s_waitcnt vmcnt(0)" ::: "memory");  // next-step staged
      __builtin_amdgcn_s_barrier();
      asm volatile("" ::: "memory");
      bo ^= 16384;
    }
    asm volatile("s_nop 7\ns_nop 7\ns_nop 7"); // MFMA->VALU hazard guard

    const int rq = lq << 2;
    if constexpr (MODE == 1) {
      // stage relu(acc+bias) tile in LDS (stride 272 spreads banks), then
      // coalesced 128B half-row stores.
#pragma unroll
      for (int n = 0; n < 4; ++n) {
        const int col = wn + (n << 4) + l15;
        const float bv = bias[g * NF + (nt << 7) + col];
#pragma unroll
        for (int m = 0; m < 4; ++m)
#pragma unroll
          for (int j = 0; j < 4; ++j) {
            const int row = wm + (m << 4) + rq + j;
            float v = acc[m][n][j] + bv;
            v = v > 0.f ? v : 0.f;
            *(__hip_bfloat16*)(LDS + row * 272 + col * 2) =
                __float2bfloat16(v);
          }
      }
      asm volatile("s_waitcnt lgkmcnt(0)" ::: "memory");  // ds_writes done
      __builtin_amdgcn_s_barrier();
      asm volatile("" ::: "memory");
      const int r = tid >> 1, hf = tid & 1;
      if (r < nrows) {
        const char* src = LDS + r * 272 + hf * 128;
        char* dst = (char*)(Hout + ((size_t)(off + (mt << 7) + r) << 11) +
                            (nt << 7)) + hf * 128;
#pragma unroll
        for (int q = 0; q < 8; ++q)
          *(s16x8*)(dst + q * 16) = *(const s16x8*)(src + q * 16);
      }
      __builtin_amdgcn_s_barrier();   // guard next tile's STAGE(0) overwrite
      asm volatile("" ::: "memory");
    } else {
#pragma unroll
      for (int n = 0; n < 4; ++n) {
        const int ncol = (nt << 7) + wn + (n << 4) + l15;
        const float bv = bias[g * NF + ncol];
#pragma unroll
        for (int m = 0; m < 4; ++m)
#pragma unroll
          for (int j = 0; j < 4; ++j) {
            const int rl = wm + (m << 4) + rq + j;
            if (rl < nrows) {
              const int tok = perm[off + (mt << 7) + rl];
              Yout[((size_t)tok << 9) + ncol] = acc[m][n][j] + bv;
            }
          }
      }
    }
  }
}

extern "C" void kernel_launch(void* const* d_in, const int* in_sizes, int n_in,
                              void* d_out, int out_size, void* d_ws,
                              size_t ws_size, hipStream_t stream) {
  const float* x    = (const float*)d_in[0];
  const int* b_seq  = (const int*)d_in[1];
  const float* W1   = (const float*)d_in[2];
  const float* B1   = (const float*)d_in[3];
  const float* W2   = (const float*)d_in[4];
  const float* B2   = (const float*)d_in[5];
  float* out        = (float*)d_out;

  char* ws = (char*)d_ws;
  int* hdr  = (int*)ws;                         // 1 KB header
  int* perm = (int*)(ws + 1024);                // 64 KB
  __hip_bfloat16* zp = (__hip_bfloat16*)(ws + 66560);       // 8 KB zeros
  __hip_bfloat16* xb = zp + 4096;
  __hip_bfloat16* W1t = xb + (size_t)NTOK * HDIM;           // [4][2048][512]
  __hip_bfloat16* W2t = W1t + (size_t)NEXP * FDIM * HDIM;   // [4][512][2048]
  __hip_bfloat16* Hws = W2t + (size_t)NEXP * HDIM * FDIM;   // [16384][2048]

  const int n4 = NTOK * HDIM / 4;

  k_init_cvt<<<2048, 256, 0, stream>>>(x, b_seq, xb, (float4*)out, n4, hdr,
                                       (float4*)zp);
  k_count_scan<<<1, 1024, 0, stream>>>((const int4*)b_seq, hdr);
  k_fill<<<NTOK / 256, 256, 0, stream>>>(b_seq, hdr, perm);
  k_transpose_cvt<<<dim3(FDIM / 32, HDIM / 32, NEXP), dim3(32, 8), 0, stream>>>(
      W1, W1t, HDIM, FDIM);
  k_transpose_cvt<<<dim3(HDIM / 32, FDIM / 32, NEXP), dim3(32, 8), 0, stream>>>(
      W2, W2t, FDIM, HDIM);
  k_gemm<1><<<2048, 256, 0, stream>>>(hdr, perm, xb, W1t, B1, zp, Hws, nullptr);
  k_gemm<2><<<512, 256, 0, stream>>>(hdr, perm, Hws, W2t, B2, zp, nullptr, out);
}